// Round 10
// baseline (662.801 us; speedup 1.0000x reference)
//
#include <hip/hip_runtime.h>
#include <cstdint>

#define P2 2654435761u
#define P3 805459861u
#define HMASK 524287u

// Spatial binning: 32x32x32 cells, z-paired into 32x32x16 = 16384
// superbuckets (avg 64 pts each at N=1M). Fixed capacity CAP=128:
// Poisson(64) P(>128) ~ 1e-13 per bucket; overflow goes to a fallback
// list. One atomic pass builds perm directly -- no scan, no scatter
// (round-8 aux pipeline cost 238 us, almost as much as the main kernel).
#define NSB 16384
#define CAP 128
#define OVF_CAP 65536
#define OVF_BLOCKS 1024   // OVF_CAP / 64

// nt builtins require native clang vector types.
// Round-5 lesson: nt LOADS bypass L2 (never on reused data).
// Round-6 lesson: gather working set must stay exactly the 4MB table.
// Round-7 lesson: dur tracks unique-line request count, not concurrency.
// Round-8 lessons: spatial sorting works (283us main); output stores must
// cover full 64B lines WITHIN one instruction or nt partial-line writes
// cause RMW traffic (WRITE 239MB vs 134, FETCH +160MB).
typedef float nfloat4 __attribute__((ext_vector_type(4)));

// int(16 * exp((ln2048-ln16)/15)**l), IEEE-double verified vs the numpy
// reference. All even => rm1 odd => even x0 never clamped (pair merge).
__constant__ int RES[16] = {16, 22, 30, 42, 58, 80, 111, 153,
                            212, 294, 406, 561, 776, 1072, 1482, 2048};

__global__ __launch_bounds__(256) void zero_counts(int* c) {
    int i = blockIdx.x * 256 + threadIdx.x;
    if (i < NSB + 1) c[i] = 0;       // counts[NSB] + novf
}

__global__ __launch_bounds__(256) void place_kernel(
    const float* __restrict__ pos, int* __restrict__ counts,
    int* __restrict__ novf, int* __restrict__ perm,
    int* __restrict__ ovfperm, int n)
{
    int i = blockIdx.x * 256 + threadIdx.x;
    if (i >= n) return;
    float px = pos[3*i], py = pos[3*i+1], pz = pos[3*i+2];
    int bx = min(31, max(0, (int)((px + 1.0f) * 16.0f)));
    int by = min(31, max(0, (int)((py + 1.0f) * 16.0f)));
    int bz = min(31, max(0, (int)((pz + 1.0f) * 16.0f)));
    int sb = (bx * 32 + by) * 16 + (bz >> 1);
    int slot = atomicAdd(&counts[sb], 1);
    if (slot < CAP) {
        perm[sb * CAP + slot] = i;
    } else {
        int o = atomicAdd(novf, 1);
        if (o < OVF_CAP) ovfperm[o] = i;
    }
}

// Main kernel: 64 spatially-adjacent points x 4 waves; wave w computes
// levels {w, w+4, w+8, w+12} with one wave-uniform level per vmem
// instruction -> spatial neighbors share table lines (coarse levels
// collapse toward broadcast). Masked-out lanes issue no requests, so
// partial blocks are nearly free.
__global__ __launch_bounds__(256) void hash_enc_sorted(
    const float* __restrict__ pos, const float2* __restrict__ tbl,
    float2* __restrict__ out, const int* __restrict__ perm,
    const int* __restrict__ ovfperm, const int* __restrict__ counts,
    const int* __restrict__ novf, int n, int usePerm)
{
    const float4* __restrict__ tbl4 = (const float4*)tbl;

    __shared__ int    sidx[64];
    __shared__ float  sx[64], sy[64], sz[64];
    __shared__ float2 sout[64][17];

    const int tid = threadIdx.x;
    const int bid = blockIdx.x;

    // Block -> point-list mapping (uniform across the block).
    int nActive, sb = 0, chunk = 0, obase = 0;
    if (usePerm) {
        if (bid < 2 * NSB) {
            sb = bid >> 1; chunk = bid & 1;
            int cnt = min(counts[sb], CAP);
            nActive = min(max(cnt - chunk * 64, 0), 64);
        } else {
            obase = (bid - 2 * NSB) * 64;
            int nov = min(*novf, OVF_CAP);
            nActive = min(max(nov - obase, 0), 64);
        }
    } else {
        nActive = min(n - bid * 64, 64);
    }
    if (nActive <= 0) return;   // uniform: whole block exits (before syncs)

    if (tid < 64) {
        int pi = -1;
        if (tid < nActive) {
            if (usePerm)
                pi = (bid < 2 * NSB) ? perm[sb * CAP + chunk * 64 + tid]
                                     : ovfperm[obase + tid];
            else
                pi = bid * 64 + tid;
        }
        sidx[tid] = pi;
        float px = 0.f, py = 0.f, pz = 0.f;
        if (pi >= 0) { px = pos[3*pi]; py = pos[3*pi+1]; pz = pos[3*pi+2]; }
        sx[tid] = (px + 1.0f) * 0.5f;
        sy[tid] = (py + 1.0f) * 0.5f;
        sz[tid] = (pz + 1.0f) * 0.5f;
    }
    __syncthreads();

    const int wave = tid >> 6, lane = tid & 63;
    const bool act = (lane < nActive);
    const float x = sx[lane], y = sy[lane], z = sz[lane];

    #pragma unroll
    for (int s = 0; s < 4; ++s) {
        const int l = wave + 4 * s;        // wave-uniform level
        if (act) {
            const int rm1 = RES[l] - 1;
            const float rf = (float)rm1;

            float sxf = x * rf, syf = y * rf, szf = z * rf;
            float fx = floorf(sxf), fy = floorf(syf), fz = floorf(szf);
            float wx = sxf - fx, wy = syf - fy, wz = szf - fz;
            int x0 = (int)fx, y0 = (int)fy, z0 = (int)fz;
            int x0c = min(max(x0, 0), rm1), x1c = min(max(x0 + 1, 0), rm1);
            int y0c = min(max(y0, 0), rm1), y1c = min(max(y0 + 1, 0), rm1);
            int z0c = min(max(z0, 0), rm1), z1c = min(max(z0 + 1, 0), rm1);

            // low 19 bits of int64 hash == low 19 bits of uint32 hash
            uint32_t hy0 = (uint32_t)y0c * P2, hy1 = (uint32_t)y1c * P2;
            uint32_t hz0 = (uint32_t)z0c * P3, hz1 = (uint32_t)z1c * P3;
            uint32_t m00 = hy0 ^ hz0, m01 = hy0 ^ hz1;
            uint32_t m10 = hy1 ^ hz0, m11 = hy1 ^ hz1;

            uint32_t hx0 = (uint32_t)x0c;
            uint32_t j000 = (hx0 ^ m00) & HMASK;
            uint32_t j001 = (hx0 ^ m01) & HMASK;
            uint32_t j010 = (hx0 ^ m10) & HMASK;
            uint32_t j011 = (hx0 ^ m11) & HMASK;

            // 4 pair loads: even x0 -> other float4 half IS the x1 corner.
            float4 q00 = tbl4[j000 >> 1];
            float4 q01 = tbl4[j001 >> 1];
            float4 q10 = tbl4[j010 >> 1];
            float4 q11 = tbl4[j011 >> 1];

            bool b00 = (j000 & 1), b01 = (j001 & 1);
            bool b10 = (j010 & 1), b11 = (j011 & 1);
            float2 c000 = b00 ? make_float2(q00.z, q00.w) : make_float2(q00.x, q00.y);
            float2 c100 = b00 ? make_float2(q00.x, q00.y) : make_float2(q00.z, q00.w);
            float2 c001 = b01 ? make_float2(q01.z, q01.w) : make_float2(q01.x, q01.y);
            float2 c101 = b01 ? make_float2(q01.x, q01.y) : make_float2(q01.z, q01.w);
            float2 c010 = b10 ? make_float2(q10.z, q10.w) : make_float2(q10.x, q10.y);
            float2 c110 = b10 ? make_float2(q10.x, q10.y) : make_float2(q10.z, q10.w);
            float2 c011 = b11 ? make_float2(q11.z, q11.w) : make_float2(q11.x, q11.y);
            float2 c111 = b11 ? make_float2(q11.x, q11.y) : make_float2(q11.z, q11.w);

            // Odd x0: fetch the true x1 corners under exec mask.
            if (x0c & 1) {
                uint32_t hx1 = (uint32_t)x1c;
                c100 = tbl[(hx1 ^ m00) & HMASK];
                c101 = tbl[(hx1 ^ m01) & HMASK];
                c110 = tbl[(hx1 ^ m10) & HMASK];
                c111 = tbl[(hx1 ^ m11) & HMASK];
            }

            float ux = 1.0f - wx, uy = 1.0f - wy, uz = 1.0f - wz;
            float w00 = ux * uy, w01 = ux * wy, w10 = wx * uy, w11 = wx * wy;
            float f0, f1;
            f0  = (w00 * uz) * c000.x; f1  = (w00 * uz) * c000.y;
            f0 += (w00 * wz) * c001.x; f1 += (w00 * wz) * c001.y;
            f0 += (w01 * uz) * c010.x; f1 += (w01 * uz) * c010.y;
            f0 += (w01 * wz) * c011.x; f1 += (w01 * wz) * c011.y;
            f0 += (w10 * uz) * c100.x; f1 += (w10 * uz) * c100.y;
            f0 += (w10 * wz) * c101.x; f1 += (w10 * wz) * c101.y;
            f0 += (w11 * uz) * c110.x; f1 += (w11 * uz) * c110.y;
            f0 += (w11 * wz) * c111.x; f1 += (w11 * wz) * c111.y;

            sout[lane][l] = make_float2(f0, f1);
        }
    }
    __syncthreads();

    // Output: 8 threads per point, 16 B each -> lanes 8k..8k+7 cover one
    // point's full 128 B contiguously WITHIN one instruction (full-line
    // nt writes; round-8's 2-instruction split caused RMW amplification).
    #pragma unroll
    for (int half = 0; half < 2; ++half) {
        int q = half * 32 + (tid >> 3);
        int part = tid & 7;
        int pi = sidx[q];
        if (pi >= 0) {
            float2 a = sout[q][part * 2], b = sout[q][part * 2 + 1];
            nfloat4 v; v.x = a.x; v.y = a.y; v.z = b.x; v.w = b.y;
            __builtin_nontemporal_store(
                v, (nfloat4*)(out + ((size_t)pi * 16 + part * 2)));
        }
    }
}

extern "C" void kernel_launch(void* const* d_in, const int* in_sizes, int n_in,
                              void* d_out, int out_size, void* d_ws, size_t ws_size,
                              hipStream_t stream) {
    const float* pos = (const float*)d_in[0];
    const float2* tbl = (const float2*)d_in[1];
    float2* out = (float2*)d_out;
    int n = in_sizes[0] / 3;

    // ws layout: counts[NSB] | novf(+pad 64) | ovfperm[OVF_CAP] | perm[NSB*CAP]
    size_t need = (size_t)(NSB + 64 + OVF_CAP + (size_t)NSB * CAP) * 4;
    int usePerm = (ws_size >= need) ? 1 : 0;
    int* counts  = (int*)d_ws;
    int* novf    = counts + NSB;
    int* ovfperm = novf + 64;
    int* perm    = ovfperm + OVF_CAP;

    if (usePerm) {
        zero_counts<<<dim3((NSB + 256) / 256), dim3(256), 0, stream>>>(counts);
        place_kernel<<<dim3((n + 255) / 256), dim3(256), 0, stream>>>(
            pos, counts, novf, perm, ovfperm, n);
    }

    unsigned grid = usePerm ? (2 * NSB + OVF_BLOCKS) : (unsigned)((n + 63) / 64);
    hash_enc_sorted<<<dim3(grid), dim3(256), 0, stream>>>(
        pos, tbl, out, perm, ovfperm, counts, novf, n, usePerm);
}

// Round 11
// 514.774 us; speedup vs baseline: 1.2876x; 1.2876x over previous
//
#include <hip/hip_runtime.h>
#include <cstdint>

#define P2 2654435761u
#define P3 805459861u
#define HMASK 524287u
#define NSB 32768   // 32^3 spatial cells, avg 32 pts/cell at N=1M

// nt builtins require native clang vector types.
// Round-5 lesson: nt LOADS bypass L2 (never on reused data).
// Round-6 lesson: gather working set must stay exactly the 4MB table.
// Round-7 lesson: dur tracks unique-line request count, not concurrency.
// Round-8 lesson: spatial sorting works (283us main @86% occ).
// Round-10 lessons: full-line epilogue fixes WRITE to exactly 134MB;
// half-empty blocks are poison (2x blocks @ ~3 active lanes -> 500us).
// => exact contiguous sort, FULL 64-pt blocks only.
typedef float nfloat4 __attribute__((ext_vector_type(4)));

// int(16 * exp((ln2048-ln16)/15)**l), IEEE-double verified vs the numpy
// reference. All even => rm1 odd => even x0 never clamped (pair merge).
__constant__ int RES[16] = {16, 22, 30, 42, 58, 80, 111, 153,
                            212, 294, 406, 561, 776, 1072, 1482, 2048};

__global__ __launch_bounds__(256) void zero_counts(int* c) {
    int i = blockIdx.x * 256 + threadIdx.x;
    if (i < NSB) c[i] = 0;
}

// Pass 1: bucket id per point (cached for scatter) + histogram.
__global__ __launch_bounds__(256) void count_kernel(
    const float* __restrict__ pos, int* __restrict__ counts,
    int* __restrict__ bucketid, int n)
{
    int i = blockIdx.x * 256 + threadIdx.x;
    if (i >= n) return;
    float px = pos[3*i], py = pos[3*i+1], pz = pos[3*i+2];
    int bx = min(31, max(0, (int)((px + 1.0f) * 16.0f)));
    int by = min(31, max(0, (int)((py + 1.0f) * 16.0f)));
    int bz = min(31, max(0, (int)((pz + 1.0f) * 16.0f)));
    int b = (bx * 32 + by) * 32 + bz;   // z fastest: z-neighbors adjacent
    bucketid[i] = b;
    atomicAdd(&counts[b], 1);
}

// 3-stage parallel exclusive scan of counts[NSB] (R8's single-block scan
// did strided global reads on one CU -- a large chunk of its 238us aux).
__global__ __launch_bounds__(256) void scanA(
    const int* __restrict__ counts, int* __restrict__ partial)
{
    __shared__ int s[256];
    int t = threadIdx.x;
    s[t] = counts[blockIdx.x * 256 + t];
    __syncthreads();
    for (int off = 128; off > 0; off >>= 1) {
        if (t < off) s[t] += s[t + off];
        __syncthreads();
    }
    if (t == 0) partial[blockIdx.x] = s[0];
}

__global__ __launch_bounds__(128) void scanB(int* partial) {
    __shared__ int s[128];
    int t = threadIdx.x;
    int orig = partial[t];
    s[t] = orig;
    __syncthreads();
    for (int off = 1; off < 128; off <<= 1) {
        int v = (t >= off) ? s[t - off] : 0;
        __syncthreads();
        s[t] += v;
        __syncthreads();
    }
    partial[t] = s[t] - orig;   // exclusive
}

__global__ __launch_bounds__(256) void scanC(
    int* __restrict__ counts, const int* __restrict__ partial)
{
    __shared__ int s[256];
    int t = threadIdx.x, base = blockIdx.x * 256;
    int orig = counts[base + t];
    s[t] = orig;
    __syncthreads();
    for (int off = 1; off < 256; off <<= 1) {
        int v = (t >= off) ? s[t - off] : 0;
        __syncthreads();
        s[t] += v;
        __syncthreads();
    }
    counts[base + t] = s[t] - orig + partial[blockIdx.x];
}

// Pass 3: place each point at its bucket cursor (reads cached bucketid,
// not pos -- saves a 12MB re-read + re-hash vs R8).
__global__ __launch_bounds__(256) void scatter_kernel(
    const int* __restrict__ bucketid, int* __restrict__ counts,
    int* __restrict__ perm, int n)
{
    int i = blockIdx.x * 256 + threadIdx.x;
    if (i >= n) return;
    int slot = atomicAdd(&counts[bucketid[i]], 1);
    perm[slot] = i;
}

// Main kernel: 64 spatially-sorted points x 4 waves; wave w computes
// levels {w, w+4, w+8, w+12}, one wave-uniform level per vmem
// instruction -> spatial neighbors share table lines (coarse levels
// collapse toward broadcast).
__global__ __launch_bounds__(256) void hash_enc_sorted(
    const float* __restrict__ pos, const float2* __restrict__ tbl,
    float2* __restrict__ out, const int* __restrict__ perm,
    int n, int usePerm)
{
    const float4* __restrict__ tbl4 = (const float4*)tbl;

    __shared__ int    sidx[64];
    __shared__ float  sx[64], sy[64], sz[64];
    __shared__ float2 sout[64][17];

    const int tid = threadIdx.x;
    const int base = blockIdx.x * 64;
    const int nActive = min(n - base, 64);

    if (tid < 64) {
        int pi = -1;
        if (tid < nActive) pi = usePerm ? perm[base + tid] : (base + tid);
        sidx[tid] = pi;
        float px = 0.f, py = 0.f, pz = 0.f;
        if (pi >= 0) { px = pos[3*pi]; py = pos[3*pi+1]; pz = pos[3*pi+2]; }
        sx[tid] = (px + 1.0f) * 0.5f;
        sy[tid] = (py + 1.0f) * 0.5f;
        sz[tid] = (pz + 1.0f) * 0.5f;
    }
    __syncthreads();

    const int wave = tid >> 6, lane = tid & 63;
    const bool act = (lane < nActive);
    const float x = sx[lane], y = sy[lane], z = sz[lane];

    #pragma unroll
    for (int s = 0; s < 4; ++s) {
        const int l = wave + 4 * s;        // wave-uniform level
        if (act) {
            const int rm1 = RES[l] - 1;
            const float rf = (float)rm1;

            float sxf = x * rf, syf = y * rf, szf = z * rf;
            float fx = floorf(sxf), fy = floorf(syf), fz = floorf(szf);
            float wx = sxf - fx, wy = syf - fy, wz = szf - fz;
            int x0 = (int)fx, y0 = (int)fy, z0 = (int)fz;
            int x0c = min(max(x0, 0), rm1), x1c = min(max(x0 + 1, 0), rm1);
            int y0c = min(max(y0, 0), rm1), y1c = min(max(y0 + 1, 0), rm1);
            int z0c = min(max(z0, 0), rm1), z1c = min(max(z0 + 1, 0), rm1);

            // low 19 bits of int64 hash == low 19 bits of uint32 hash
            uint32_t hy0 = (uint32_t)y0c * P2, hy1 = (uint32_t)y1c * P2;
            uint32_t hz0 = (uint32_t)z0c * P3, hz1 = (uint32_t)z1c * P3;
            uint32_t m00 = hy0 ^ hz0, m01 = hy0 ^ hz1;
            uint32_t m10 = hy1 ^ hz0, m11 = hy1 ^ hz1;

            uint32_t hx0 = (uint32_t)x0c;
            uint32_t j000 = (hx0 ^ m00) & HMASK;
            uint32_t j001 = (hx0 ^ m01) & HMASK;
            uint32_t j010 = (hx0 ^ m10) & HMASK;
            uint32_t j011 = (hx0 ^ m11) & HMASK;

            // 4 pair loads: even x0 -> other float4 half IS the x1 corner.
            float4 q00 = tbl4[j000 >> 1];
            float4 q01 = tbl4[j001 >> 1];
            float4 q10 = tbl4[j010 >> 1];
            float4 q11 = tbl4[j011 >> 1];

            bool b00 = (j000 & 1), b01 = (j001 & 1);
            bool b10 = (j010 & 1), b11 = (j011 & 1);
            float2 c000 = b00 ? make_float2(q00.z, q00.w) : make_float2(q00.x, q00.y);
            float2 c100 = b00 ? make_float2(q00.x, q00.y) : make_float2(q00.z, q00.w);
            float2 c001 = b01 ? make_float2(q01.z, q01.w) : make_float2(q01.x, q01.y);
            float2 c101 = b01 ? make_float2(q01.x, q01.y) : make_float2(q01.z, q01.w);
            float2 c010 = b10 ? make_float2(q10.z, q10.w) : make_float2(q10.x, q10.y);
            float2 c110 = b10 ? make_float2(q10.x, q10.y) : make_float2(q10.z, q10.w);
            float2 c011 = b11 ? make_float2(q11.z, q11.w) : make_float2(q11.x, q11.y);
            float2 c111 = b11 ? make_float2(q11.x, q11.y) : make_float2(q11.z, q11.w);

            // Odd x0: fetch the true x1 corners under exec mask.
            if (x0c & 1) {
                uint32_t hx1 = (uint32_t)x1c;
                c100 = tbl[(hx1 ^ m00) & HMASK];
                c101 = tbl[(hx1 ^ m01) & HMASK];
                c110 = tbl[(hx1 ^ m10) & HMASK];
                c111 = tbl[(hx1 ^ m11) & HMASK];
            }

            float ux = 1.0f - wx, uy = 1.0f - wy, uz = 1.0f - wz;
            float w00 = ux * uy, w01 = ux * wy, w10 = wx * uy, w11 = wx * wy;
            float f0, f1;
            f0  = (w00 * uz) * c000.x; f1  = (w00 * uz) * c000.y;
            f0 += (w00 * wz) * c001.x; f1 += (w00 * wz) * c001.y;
            f0 += (w01 * uz) * c010.x; f1 += (w01 * uz) * c010.y;
            f0 += (w01 * wz) * c011.x; f1 += (w01 * wz) * c011.y;
            f0 += (w10 * uz) * c100.x; f1 += (w10 * uz) * c100.y;
            f0 += (w10 * wz) * c101.x; f1 += (w10 * wz) * c101.y;
            f0 += (w11 * uz) * c110.x; f1 += (w11 * uz) * c110.y;
            f0 += (w11 * wz) * c111.x; f1 += (w11 * wz) * c111.y;

            sout[lane][l] = make_float2(f0, f1);
        }
    }
    __syncthreads();

    // Epilogue (verified round 10: WRITE exactly 134MB): 8 threads/point,
    // 16B each -> one point's full 128B line covered WITHIN one
    // instruction; nt (write-once) keeps L2 for the table.
    #pragma unroll
    for (int half = 0; half < 2; ++half) {
        int q = half * 32 + (tid >> 3);
        int part = tid & 7;
        int pi = sidx[q];
        if (pi >= 0) {
            float2 a = sout[q][part * 2], b = sout[q][part * 2 + 1];
            nfloat4 v; v.x = a.x; v.y = a.y; v.z = b.x; v.w = b.y;
            __builtin_nontemporal_store(
                v, (nfloat4*)(out + ((size_t)pi * 16 + part * 2)));
        }
    }
}

extern "C" void kernel_launch(void* const* d_in, const int* in_sizes, int n_in,
                              void* d_out, int out_size, void* d_ws, size_t ws_size,
                              hipStream_t stream) {
    const float* pos = (const float*)d_in[0];
    const float2* tbl = (const float2*)d_in[1];
    float2* out = (float2*)d_out;
    int n = in_sizes[0] / 3;

    // ws: counts[NSB] | partial[128] | bucketid[n] | perm[n]
    size_t need = (size_t)(NSB + 128 + 2 * (size_t)n) * 4;
    int usePerm = (ws_size >= need) ? 1 : 0;
    int* counts   = (int*)d_ws;
    int* partial  = counts + NSB;
    int* bucketid = partial + 128;
    int* perm     = bucketid + n;

    if (usePerm) {
        zero_counts<<<dim3(NSB / 256), dim3(256), 0, stream>>>(counts);
        count_kernel<<<dim3((n + 255) / 256), dim3(256), 0, stream>>>(
            pos, counts, bucketid, n);
        scanA<<<dim3(NSB / 256), dim3(256), 0, stream>>>(counts, partial);
        scanB<<<dim3(1), dim3(128), 0, stream>>>(partial);
        scanC<<<dim3(NSB / 256), dim3(256), 0, stream>>>(counts, partial);
        scatter_kernel<<<dim3((n + 255) / 256), dim3(256), 0, stream>>>(
            bucketid, counts, perm, n);
    }

    hash_enc_sorted<<<dim3((n + 63) / 64), dim3(256), 0, stream>>>(
        pos, tbl, out, perm, n, usePerm);
}